// Round 5
// baseline (1577.397 us; speedup 1.0000x reference)
//
#include <hip/hip_runtime.h>
#include <math.h>

// WanModel transformer block. Round 7: M64 GEMM variant (tile 64x128, 36KB
// LDS, grid 2x) for the grid-starved N=1536 GEMMs (O, crossQ, crossO, FFN2)
// and cross-KV; 128x128 variant kept for QKV/FFN1.  Attn unchanged (swapped
// QK^T, base-2 softmax).
// L=4032 (pad 4096), C=1536, NH=12, D=128, L2=512, FFN=8960.

#define L_SEQ 4032
#define L_PAD 4096
#define C_DIM 1536
#define L_CTX 512
#define FFN_DIM 8960
#define NHEAD 12
#define DHEAD 128

typedef __attribute__((ext_vector_type(8))) short short8;
typedef __attribute__((ext_vector_type(4))) float floatx4;

__device__ inline unsigned short f2bf(float x) {  // RNE f32 -> bf16
  unsigned int u = __float_as_uint(x);
  u += 0x7fffu + ((u >> 16) & 1u);
  return (unsigned short)(u >> 16);
}

// ---------------- block-wide reduction (256 threads = 4 waves) --------------
__device__ inline float2 block_sum2(float2 v) {
  __shared__ float2 red[4];
#pragma unroll
  for (int o = 32; o > 0; o >>= 1) {
    v.x += __shfl_xor(v.x, o, 64);
    v.y += __shfl_xor(v.y, o, 64);
  }
  int wave = threadIdx.x >> 6;
  if ((threadIdx.x & 63) == 0) red[wave] = v;
  __syncthreads();
  float2 t = make_float2(0.f, 0.f);
#pragma unroll
  for (int i = 0; i < 4; ++i) { t.x += red[i].x; t.y += red[i].y; }
  return t;
}

// ---------------- small elementwise kernels --------------------------------
__global__ void add_kernel(float* __restrict__ o, const float* __restrict__ a,
                           const float* __restrict__ b, int n) {
  int i = blockIdx.x * 256 + threadIdx.x;
  if (i < n) o[i] = a[i] + b[i];
}

__global__ void concat3_kernel(float* __restrict__ o, const float* __restrict__ a,
                               const float* __restrict__ b, const float* __restrict__ c) {
  int i = blockIdx.x * 256 + threadIdx.x;
  if (i < C_DIM) {
    o[i] = a[i];
    o[C_DIM + i] = b[i];
    if (c) o[2 * C_DIM + i] = c[i];
  }
}

__global__ void f32_to_bf16_kernel(unsigned short* __restrict__ o,
                                   const float* __restrict__ in, int n) {
  int i = (blockIdx.x * 256 + threadIdx.x) * 4;
  if (i < n) {
    float4 v = *(const float4*)&in[i];
    ushort4 o4 = {f2bf(v.x), f2bf(v.y), f2bf(v.z), f2bf(v.w)};
    *(ushort4*)&o[i] = o4;
  }
}

// W (K x N fp32, row-major) -> WT (N x K bf16, row-major)
__global__ __launch_bounds__(256) void transpose_bf16_kernel(
    const float* __restrict__ W, unsigned short* __restrict__ WT, int K, int N) {
  __shared__ float t[32][33];
  int n0 = blockIdx.x * 32, k0 = blockIdx.y * 32;
  int c = threadIdx.x & 31, r0 = threadIdx.x >> 5;
#pragma unroll
  for (int i = 0; i < 4; ++i) {
    int r = r0 + 8 * i;
    t[r][c] = W[(size_t)(k0 + r) * N + n0 + c];
  }
  __syncthreads();
#pragma unroll
  for (int i = 0; i < 4; ++i) {
    int r = r0 + 8 * i;
    WT[(size_t)(n0 + r) * K + k0 + c] = f2bf(t[c][r]);
  }
}

// V slice (Lk rows, stride floats) -> Vt (C x Lk bf16)
__global__ __launch_bounds__(256) void transpose_v_kernel(
    const float* __restrict__ V, unsigned short* __restrict__ Vt, int stride, int Lk) {
  __shared__ float t[32][33];
  int k0 = blockIdx.x * 32, c0 = blockIdx.y * 32;
  int c = threadIdx.x & 31, r0 = threadIdx.x >> 5;
#pragma unroll
  for (int i = 0; i < 4; ++i) {
    int r = r0 + 8 * i;
    t[r][c] = V[(size_t)(k0 + r) * stride + c0 + c];
  }
  __syncthreads();
#pragma unroll
  for (int i = 0; i < 4; ++i) {
    int r = r0 + 8 * i;
    Vt[(size_t)(c0 + r) * Lk + k0 + c] = f2bf(t[c][r]);
  }
}

// ---------------- LayerNorm with affine, bf16 output -----------------------
__global__ __launch_bounds__(256) void ln_affine_kernel(
    unsigned short* __restrict__ out, const float* __restrict__ in,
    const float* __restrict__ sc, const float* __restrict__ sh, float addOne) {
  int row = blockIdx.x;
  const float* xr = in + (size_t)row * C_DIM;
  float vals[C_DIM / 256];
  float2 p = make_float2(0.f, 0.f);
  int cnt = 0;
  for (int c = threadIdx.x; c < C_DIM; c += 256) {
    float v = xr[c];
    vals[cnt++] = v;
    p.x += v; p.y += v * v;
  }
  float2 t = block_sum2(p);
  float mean = t.x * (1.f / C_DIM);
  float var = t.y * (1.f / C_DIM) - mean * mean;
  float r = rsqrtf(var + 1e-6f);
  cnt = 0;
  for (int c = threadIdx.x; c < C_DIM; c += 256) {
    float xh = (vals[cnt++] - mean) * r;
    out[(size_t)row * C_DIM + c] = f2bf(xh * (addOne + sc[c]) + sh[c]);
  }
}

// ---------------- fused RMS norm (+RoPE) + bf16 cast -----------------------
// ps: extra scalar folded into the output (used to pre-scale Q by
// log2(e)/sqrt(d); commutes with the RoPE rotation).
template <int ROPE>
__global__ __launch_bounds__(256) void rms_post_kernel(
    unsigned short* __restrict__ obf, const float* __restrict__ in,
    const float* __restrict__ w, const float* __restrict__ cosb,
    const float* __restrict__ sinb, int stride, float ps) {
  int row = blockIdx.x;
  const float* xr = in + (size_t)row * stride;
  int c0 = threadIdx.x * 6;
  float v[6];
  *(float2*)&v[0] = *(const float2*)&xr[c0];
  *(float2*)&v[2] = *(const float2*)&xr[c0 + 2];
  *(float2*)&v[4] = *(const float2*)&xr[c0 + 4];
  float s2 = 0.f;
#pragma unroll
  for (int i = 0; i < 6; ++i) s2 += v[i] * v[i];
  float2 t = block_sum2(make_float2(s2, 0.f));
  float r = rsqrtf(t.x * (1.f / C_DIM) + 1e-6f) * ps;
#pragma unroll
  for (int i = 0; i < 6; ++i) v[i] *= r * w[c0 + i];
  if (ROPE) {
#pragma unroll
    for (int i = 0; i < 3; ++i) {
      int c = c0 + 2 * i;
      int j = (c & 127) >> 1;
      float co = cosb[row * 64 + j], si = sinb[row * 64 + j];
      float a = v[2 * i], b = v[2 * i + 1];
      v[2 * i] = a * co - b * si;
      v[2 * i + 1] = a * si + b * co;
    }
  }
  unsigned short* op = obf + (size_t)row * C_DIM + c0;
  ushort2 o01 = {f2bf(v[0]), f2bf(v[1])};
  ushort2 o23 = {f2bf(v[2]), f2bf(v[3])};
  ushort2 o45 = {f2bf(v[4]), f2bf(v[5])};
  *(ushort2*)&op[0] = o01;
  *(ushort2*)&op[2] = o23;
  *(ushort2*)&op[4] = o45;
}

// ---------------- RoPE tables ----------------------------------------------
__global__ void rope_tables_kernel(float* __restrict__ cosb, float* __restrict__ sinb) {
  int l = blockIdx.x, j = threadIdx.x;  // 64 threads
  int f = l / (16 * 28);
  int rem = l % (16 * 28);
  int hh = rem / 28, ww = rem % 28;
  double inv = pow(10000.0, -(double)(2 * j) / 128.0);
  double pos = (j < 22) ? (double)f : ((j < 43) ? (double)hh : (double)ww);
  double ang = pos * inv;
  cosb[l * 64 + j] = (float)cos(ang);
  sinb[l * 64 + j] = (float)sin(ang);
}

__device__ inline float gelu_tanh(float x) {
  float x3 = x * x * x;
  return 0.5f * x * (1.f + tanhf(0.79788456080286535588f * (x + 0.044715f * x3)));
}

// XCD-chunked bijective remap of the flat block index (T1 / m204)
__device__ inline int xcd_remap(int flat, int nwg) {
  int qq = nwg >> 3, rr = nwg & 7;
  int xcd = flat & 7, idx = flat >> 3;
  return (xcd < rr ? xcd * (qq + 1) : rr * (qq + 1) + (xcd - rr) * qq) + idx;
}

// ---------------- bf16 MFMA GEMM, tile 128x128 (3-buffer, vmcnt(4)) --------
// C[m][n] = sum_k A[m][k]*BT[n][k] + bias[n].  A: bf16 (Mpad x K), BT: bf16
// (N x K), row-major.  N%128==0, K%32==0 (K>=96).  Block 256 = 4 waves, each
// wave 64x64.  Depth-2 prefetch, raw s_barrier + counted vmcnt(4).
// EPI: 0 = f32 out; 1 = gelu+bf16; 2 = resid + v*gate f32.
template <int EPI>
__global__ __launch_bounds__(256) void mgemm_kernel(
    const unsigned short* __restrict__ A, const unsigned short* __restrict__ BT,
    const float* __restrict__ bias, void* __restrict__ Cout,
    const float* __restrict__ resid, const float* __restrict__ gate,
    int N, int K, int Mlimit) {
  __shared__ short sA[3][4096];  // 128 x 32 bf16, fragment order
  __shared__ short sB[3][4096];
  const int tid = threadIdx.x;
  const int wv = tid >> 6, lane = tid & 63;
  const int lm = lane & 15, lq = lane >> 4;
  const int wr = wv >> 1, wc = wv & 1;

  const int gx = gridDim.x;
  int flat = xcd_remap(blockIdx.y * gx + blockIdx.x, gx * gridDim.y);
  const int row0 = (flat / gx) * 128, col0 = (flat % gx) * 128;

  floatx4 zero4 = {0.f, 0.f, 0.f, 0.f};
  floatx4 acc[4][4];
#pragma unroll
  for (int i = 0; i < 4; ++i)
#pragma unroll
    for (int j = 0; j < 4; ++j) acc[i][j] = zero4;

  const unsigned short* Abase = A + ((size_t)row0 + lm) * K + lq * 8;
  const unsigned short* Bbase = BT + ((size_t)col0 + lm) * K + lq * 8;

  auto stage = [&](int buf, int k0) {
#pragma unroll
    for (int t = 0; t < 2; ++t) {
      int g = wv * 2 + t;
      __builtin_amdgcn_global_load_lds(
          (const __attribute__((address_space(1))) void*)(Abase + (size_t)(g * 16) * K + k0),
          (__attribute__((address_space(3))) void*)(sA[buf] + g * 512), 16, 0, 0);
      __builtin_amdgcn_global_load_lds(
          (const __attribute__((address_space(1))) void*)(Bbase + (size_t)(g * 16) * K + k0),
          (__attribute__((address_space(3))) void*)(sB[buf] + g * 512), 16, 0, 0);
    }
  };

  stage(0, 0);
  stage(1, 32);
  asm volatile("s_waitcnt vmcnt(4)" ::: "memory");  // buf0 loads done
  __builtin_amdgcn_s_barrier();
  __builtin_amdgcn_sched_barrier(0);

  int cur = 0;
  const int nk = K >> 5;
  for (int t = 0; t < nk; ++t) {
    int b2 = cur + 2; if (b2 >= 3) b2 -= 3;
    const bool more = (t + 2 < nk);
    if (more) stage(b2, (t + 2) << 5);  // depth-2 prefetch
    const short* sAc = &sA[cur][0];
    const short* sBc = &sB[cur][0];
    short8 af[4], bfv[4];
#pragma unroll
    for (int mt = 0; mt < 4; ++mt)
      af[mt] = *(const short8*)(sAc + (wr * 4 + mt) * 512 + lane * 8);
#pragma unroll
    for (int nt = 0; nt < 4; ++nt)
      bfv[nt] = *(const short8*)(sBc + (wc * 4 + nt) * 512 + lane * 8);
#pragma unroll
    for (int mt = 0; mt < 4; ++mt)
#pragma unroll
      for (int nt = 0; nt < 4; ++nt)
        acc[mt][nt] = __builtin_amdgcn_mfma_f32_16x16x32_bf16(
            af[mt], bfv[nt], acc[mt][nt], 0, 0, 0);
    __builtin_amdgcn_sched_barrier(0);
    if (more) { asm volatile("s_waitcnt vmcnt(4)" ::: "memory"); }  // t+1 ready
    else      { asm volatile("s_waitcnt vmcnt(0)" ::: "memory"); }  // tail drain
    __builtin_amdgcn_s_barrier();
    __builtin_amdgcn_sched_barrier(0);
    cur = (cur + 1 == 3) ? 0 : cur + 1;
  }

  // epilogue: C/D layout col = lane&15, row = (lane>>4)*4 + reg
#pragma unroll
  for (int nt = 0; nt < 4; ++nt) {
    int colg = col0 + wc * 64 + nt * 16 + lm;
    float bv = bias[colg];
    float gv = (EPI == 2 && gate) ? gate[colg] : 1.f;
#pragma unroll
    for (int mt = 0; mt < 4; ++mt) {
#pragma unroll
      for (int r = 0; r < 4; ++r) {
        int rowg = row0 + wr * 64 + mt * 16 + lq * 4 + r;
        if (rowg < Mlimit) {
          float v = acc[mt][nt][r] + bv;
          if (EPI == 1) {
            ((unsigned short*)Cout)[(size_t)rowg * N + colg] = f2bf(gelu_tanh(v));
          } else if (EPI == 2) {
            ((float*)Cout)[(size_t)rowg * N + colg] =
                resid[(size_t)rowg * N + colg] + v * gv;
          } else {
            ((float*)Cout)[(size_t)rowg * N + colg] = v;
          }
        }
      }
    }
  }
}

// ---------------- bf16 MFMA GEMM, tile 64x128 (occupancy variant) ----------
// Same contract as mgemm_kernel but M-tile 64: grid.y = Mpad/64.  4 waves,
// each owns 64x32 (acc 4x2).  LDS 36KB -> 4 blocks/CU cap; doubles the grid
// for the N=1536 GEMMs (384 -> 768 blocks => 12 waves/CU instead of 6).
// Per-wave staging = 1 A-load + 2 B-loads per tile -> counted vmcnt(3).
template <int EPI>
__global__ __launch_bounds__(256) void mgemm64_kernel(
    const unsigned short* __restrict__ A, const unsigned short* __restrict__ BT,
    const float* __restrict__ bias, void* __restrict__ Cout,
    const float* __restrict__ resid, const float* __restrict__ gate,
    int N, int K, int Mlimit) {
  __shared__ short sA[3][2048];  // 64 x 32 bf16, fragment order (4 chunks)
  __shared__ short sB[3][4096];  // 128 x 32 bf16 (8 chunks)
  const int tid = threadIdx.x;
  const int wv = tid >> 6, lane = tid & 63;
  const int lm = lane & 15, lq = lane >> 4;
  const int wc = wv;  // 4 column groups of 32

  const int gx = gridDim.x;
  int flat = xcd_remap(blockIdx.y * gx + blockIdx.x, gx * gridDim.y);
  const int row0 = (flat / gx) * 64, col0 = (flat % gx) * 128;

  floatx4 zero4 = {0.f, 0.f, 0.f, 0.f};
  floatx4 acc[4][2];
#pragma unroll
  for (int i = 0; i < 4; ++i)
#pragma unroll
    for (int j = 0; j < 2; ++j) acc[i][j] = zero4;

  const unsigned short* Abase = A + ((size_t)row0 + lm) * K + lq * 8;
  const unsigned short* Bbase = BT + ((size_t)col0 + lm) * K + lq * 8;

  auto stage = [&](int buf, int k0) {
    __builtin_amdgcn_global_load_lds(
        (const __attribute__((address_space(1))) void*)(Abase + (size_t)(wv * 16) * K + k0),
        (__attribute__((address_space(3))) void*)(sA[buf] + wv * 512), 16, 0, 0);
#pragma unroll
    for (int t = 0; t < 2; ++t) {
      int g = wv * 2 + t;
      __builtin_amdgcn_global_load_lds(
          (const __attribute__((address_space(1))) void*)(Bbase + (size_t)(g * 16) * K + k0),
          (__attribute__((address_space(3))) void*)(sB[buf] + g * 512), 16, 0, 0);
    }
  };

  stage(0, 0);
  stage(1, 32);
  asm volatile("s_waitcnt vmcnt(3)" ::: "memory");  // buf0 loads done
  __builtin_amdgcn_s_barrier();
  __builtin_amdgcn_sched_barrier(0);

  int cur = 0;
  const int nk = K >> 5;
  for (int t = 0; t < nk; ++t) {
    int b2 = cur + 2; if (b2 >= 3) b2 -= 3;
    const bool more = (t + 2 < nk);
    if (more) stage(b2, (t + 2) << 5);  // depth-2 prefetch
    const short* sAc = &sA[cur][0];
    const short* sBc = &sB[cur][0];
    short8 af[4], bfv[2];
#pragma unroll
    for (int mt = 0; mt < 4; ++mt)
      af[mt] = *(const short8*)(sAc + mt * 512 + lane * 8);
#pragma unroll
    for (int nt = 0; nt < 2; ++nt)
      bfv[nt] = *(const short8*)(sBc + (wc * 2 + nt) * 512 + lane * 8);
#pragma unroll
    for (int mt = 0; mt < 4; ++mt)
#pragma unroll
      for (int nt = 0; nt < 2; ++nt)
        acc[mt][nt] = __builtin_amdgcn_mfma_f32_16x16x32_bf16(
            af[mt], bfv[nt], acc[mt][nt], 0, 0, 0);
    __builtin_amdgcn_sched_barrier(0);
    if (more) { asm volatile("s_waitcnt vmcnt(3)" ::: "memory"); }  // t+1 ready
    else      { asm volatile("s_waitcnt vmcnt(0)" ::: "memory"); }  // tail drain
    __builtin_amdgcn_s_barrier();
    __builtin_amdgcn_sched_barrier(0);
    cur = (cur + 1 == 3) ? 0 : cur + 1;
  }

  // epilogue
#pragma unroll
  for (int nt = 0; nt < 2; ++nt) {
    int colg = col0 + wc * 32 + nt * 16 + lm;
    float bv = bias[colg];
    float gv = (EPI == 2 && gate) ? gate[colg] : 1.f;
#pragma unroll
    for (int mt = 0; mt < 4; ++mt) {
#pragma unroll
      for (int r = 0; r < 4; ++r) {
        int rowg = row0 + mt * 16 + lq * 4 + r;
        if (rowg < Mlimit) {
          float v = acc[mt][nt][r] + bv;
          if (EPI == 1) {
            ((unsigned short*)Cout)[(size_t)rowg * N + colg] = f2bf(gelu_tanh(v));
          } else if (EPI == 2) {
            ((float*)Cout)[(size_t)rowg * N + colg] =
                resid[(size_t)rowg * N + colg] + v * gv;
          } else {
            ((float*)Cout)[(size_t)rowg * N + colg] = v;
          }
        }
      }
    }
  }
}

// ---------------- bf16 MFMA flash attention (swapped QK^T) -----------------
// Qb: bf16 (rows x C_DIM), PRE-SCALED by log2(e)/sqrt(d).  Kb: bf16.
// Vt: bf16 (C_DIM x Lk), Vt[h*128+d][k] = V[k][h*128+d].
// O: bf16 (rows x C_DIM).  Grid (L/64, NHEAD), block 256 = 4 waves.
// Wave w owns Q rows q0+w*16..+15.  Per 32-key tile: S^T = mfma(Kfrag, Qfrag)
// puts q = lane&15, k = nt*16 + (lane>>4)*4 + r -> each lane holds 8 scores
// of ONE q-row: row max/sum = 7 reg ops + 2 shuffles (xor 16,32).  m,l are
// per-thread scalars (q=lm domain); rescale/output cross to the acc domain
// (q=lq*4+r) via 4 __shfl.  P packed to bf16 and written as 2x ds_write_b64
// in A-frag order; PV unchanged.  Base-2 softmax, defer-max THR=11.5.
__global__ __launch_bounds__(256) void attn_mfma_kernel(
    const unsigned short* __restrict__ Qb, const unsigned short* __restrict__ Kb,
    const unsigned short* __restrict__ Vt, unsigned short* __restrict__ O,
    int Lk) {
  __shared__ short sK[2][4096];  // 8 groups (nt,dc): k-row k0+nt*16+lm, d=dc*32+lq*8
  __shared__ short sV[2][4096];  // 8 groups dg: d-row dg*16+lm, k=k0+lq*8
  __shared__ short sP[4][512];   // per-wave 16x32 P tile, A-frag order
  const int h = blockIdx.y;
  const int q0 = blockIdx.x * 64;
  const int tid = threadIdx.x;
  const int wv = tid >> 6, lane = tid & 63;
  const int lm = lane & 15, lq = lane >> 4;

  // Q fragments in registers: row = q0+wv*16+lm, d = dc*32 + lq*8
  short8 qf[4];
  {
    const unsigned short* qrow =
        Qb + (size_t)(q0 + wv * 16 + lm) * C_DIM + h * DHEAD + lq * 8;
#pragma unroll
    for (int dc = 0; dc < 4; ++dc) qf[dc] = *(const short8*)(qrow + dc * 32);
  }

  floatx4 zero4 = {0.f, 0.f, 0.f, 0.f};
  floatx4 acc[8];  // O accum: acc[dg][r] -> row lq*4+r, col dg*16+lm
#pragma unroll
  for (int g = 0; g < 8; ++g) acc[g] = zero4;
  float m = -1e30f, l = 0.f;  // per-thread, q = lm domain

  auto stageKV = [&](int buf, int k0) {
#pragma unroll
    for (int t = 0; t < 2; ++t) {
      int g = wv * 2 + t;
      int nt_ = g >> 2, dc = g & 3;
      const unsigned short* srck =
          Kb + (size_t)(k0 + nt_ * 16 + lm) * C_DIM + h * DHEAD + dc * 32 + lq * 8;
      __builtin_amdgcn_global_load_lds(
          (const __attribute__((address_space(1))) void*)srck,
          (__attribute__((address_space(3))) void*)(sK[buf] + g * 512), 16, 0, 0);
      const unsigned short* srcv =
          Vt + (size_t)(h * DHEAD + g * 16 + lm) * Lk + k0 + lq * 8;
      __builtin_amdgcn_global_load_lds(
          (const __attribute__((address_space(1))) void*)srcv,
          (__attribute__((address_space(3))) void*)(sV[buf] + g * 512), 16, 0, 0);
    }
  };

  stageKV(0, 0);
  __syncthreads();
  int cur = 0;
  const int nsteps = Lk >> 5;
  for (int t = 0; t < nsteps; ++t) {
    if (t + 1 < nsteps) stageKV(cur ^ 1, (t + 1) << 5);  // prefetch next tile
    const short* sKc = &sK[cur][0];
    const short* sVc = &sV[cur][0];

    // S^T = K * Q^T: lane (lq,lm) gets S[k=nt*16+lq*4+r][q=lm]
    floatx4 s0 = zero4, s1 = zero4;
#pragma unroll
    for (int dc = 0; dc < 4; ++dc) {
      short8 kf0 = *(const short8*)(sKc + dc * 512 + lane * 8);
      short8 kf1 = *(const short8*)(sKc + (4 + dc) * 512 + lane * 8);
      s0 = __builtin_amdgcn_mfma_f32_16x16x32_bf16(kf0, qf[dc], s0, 0, 0, 0);
      s1 = __builtin_amdgcn_mfma_f32_16x16x32_bf16(kf1, qf[dc], s1, 0, 0, 0);
    }

    // row max: 7 reg fmax + 2 shuffles across the lq chain
    float mx = fmaxf(fmaxf(fmaxf(s0[0], s0[1]), fmaxf(s0[2], s0[3])),
                     fmaxf(fmaxf(s1[0], s1[1]), fmaxf(s1[2], s1[3])));
    mx = fmaxf(mx, __shfl_xor(mx, 16));
    mx = fmaxf(mx, __shfl_xor(mx, 32));
    bool need = mx > m + 11.5f;  // defer-max (log2 domain)
    if (__any((int)need)) {
      float mn = fmaxf(m, mx);
      float al = exp2f(m - mn);
      m = mn;
      l *= al;
      float ar[4];
#pragma unroll
      for (int r = 0; r < 4; ++r) ar[r] = __shfl(al, lq * 4 + r);  // q-domain xpose
#pragma unroll
      for (int g = 0; g < 8; ++g)
#pragma unroll
        for (int r = 0; r < 4; ++r) acc[g][r] *= ar[r];
    }
    // P = 2^(S - m); pack to bf16; row-sum
    float rs = 0.f;
    ushort4 pk0, pk1;
#pragma unroll
    for (int r = 0; r < 4; ++r) {
      float p = exp2f(s0[r] - m);
      rs += p;
      ((unsigned short*)&pk0)[r] = f2bf(p);
    }
#pragma unroll
    for (int r = 0; r < 4; ++r) {
      float p = exp2f(s1[r] - m);
      rs += p;
      ((unsigned short*)&pk1)[r] = f2bf(p);
    }
    rs += __shfl_xor(rs, 16);
    rs += __shfl_xor(rs, 32);
    l += rs;
    // write P to sP in A-frag chunk order: value (q=lm, k=nt*16+lq*4+r) ->
    // short ((nt*2+(lq>>1))*16+lm)*8 + (lq&1)*4 + r ; r-contiguous -> b64
    {
      int baseq = (((lq >> 1) * 16 + lm) << 3) + ((lq & 1) << 2);
      *(ushort4*)&sP[wv][baseq] = pk0;
      *(ushort4*)&sP[wv][baseq + 256] = pk1;
    }
    asm volatile("" ::: "memory");  // keep DS write->read program order
    // PV: A = P[16q x 32k] frag, B = Vt d-rows (contraction over 32 keys)
    short8 pa = *(const short8*)(&sP[wv][lane * 8]);
#pragma unroll
    for (int g = 0; g < 8; ++g) {
      short8 vf = *(const short8*)(sVc + g * 512 + lane * 8);
      acc[g] = __builtin_amdgcn_mfma_f32_16x16x32_bf16(pa, vf, acc[g], 0, 0, 0);
    }
    __syncthreads();  // drains prefetch vmcnt + lgkm; next tile ready
    cur ^= 1;
  }

  float invl[4];
#pragma unroll
  for (int r = 0; r < 4; ++r) invl[r] = 1.f / __shfl(l, lq * 4 + r);
  unsigned short* orow =
      O + (size_t)(q0 + wv * 16 + lq * 4) * C_DIM + h * DHEAD + lm;
#pragma unroll
  for (int g = 0; g < 8; ++g) {
#pragma unroll
    for (int r = 0; r < 4; ++r) {
      orow[(size_t)r * C_DIM + g * 16] = f2bf(acc[g][r] * invl[r]);
    }
  }
}

// ---------------- orchestration --------------------------------------------
extern "C" void kernel_launch(void* const* d_in, const int* in_sizes, int n_in,
                              void* d_out, int out_size, void* d_ws, size_t ws_size,
                              hipStream_t stream) {
  const float* x     = (const float*)d_in[0];
  const float* e     = (const float*)d_in[1];
  const float* ctx   = (const float*)d_in[2];
  const float* mod   = (const float*)d_in[3];
  const float* sa_wq = (const float*)d_in[4];
  const float* sa_bq = (const float*)d_in[5];
  const float* sa_wk = (const float*)d_in[6];
  const float* sa_bk = (const float*)d_in[7];
  const float* sa_wv = (const float*)d_in[8];
  const float* sa_bv = (const float*)d_in[9];
  const float* sa_wo = (const float*)d_in[10];
  const float* sa_bo = (const float*)d_in[11];
  const float* sa_nq = (const float*)d_in[12];
  const float* sa_nk = (const float*)d_in[13];
  const float* n3_w  = (const float*)d_in[14];
  const float* n3_b  = (const float*)d_in[15];
  const float* ca_wq = (const float*)d_in[16];
  const float* ca_bq = (const float*)d_in[17];
  const float* ca_wk = (const float*)d_in[18];
  const float* ca_bk = (const float*)d_in[19];
  const float* ca_wv = (const float*)d_in[20];
  const float* ca_bv = (const float*)d_in[21];
  const float* ca_wo = (const float*)d_in[22];
  const float* ca_bo = (const float*)d_in[23];
  const float* ca_nq = (const float*)d_in[24];
  const float* ca_nk = (const float*)d_in[25];
  const float* ffn_w1 = (const float*)d_in[26];
  const float* ffn_b1 = (const float*)d_in[27];
  const float* ffn_w2 = (const float*)d_in[28];
  const float* ffn_b2 = (const float*)d_in[29];
  float* out = (float*)d_out;

  char* wsb = (char*)d_ws;
  auto alloc_f = [&](size_t n) { float* p = (float*)wsb; wsb += ((n * 4 + 255) / 256) * 256; return p; };
  auto alloc_h = [&](size_t n) { unsigned short* p = (unsigned short*)wsb; wsb += ((n * 2 + 255) / 256) * 256; return p; };

  float* em   = alloc_f(6 * C_DIM);
  float* cosb = alloc_f(L_SEQ * 64);
  float* sinb = alloc_f(L_SEQ * 64);
  float* qkv  = alloc_f((size_t)L_SEQ * 3 * C_DIM);  // fused QKV f32 out
  float* x1b  = alloc_f((size_t)L_SEQ * C_DIM);
  unsigned short* act_bf  = alloc_h((size_t)L_PAD * C_DIM);
  unsigned short* ctx_bf  = alloc_h((size_t)L_CTX * C_DIM);
  unsigned short* wtqkv = alloc_h((size_t)3 * C_DIM * C_DIM);
  unsigned short* wto   = alloc_h((size_t)C_DIM * C_DIM);
  unsigned short* wtcq  = alloc_h((size_t)C_DIM * C_DIM);
  unsigned short* wtckv = alloc_h((size_t)2 * C_DIM * C_DIM);
  unsigned short* wtco  = alloc_h((size_t)C_DIM * C_DIM);
  unsigned short* wt1   = alloc_h((size_t)FFN_DIM * C_DIM);  // (8960 x 1536)
  unsigned short* wt2   = alloc_h((size_t)C_DIM * FFN_DIM);  // (1536 x 8960)
  float* qkv_bias = alloc_f(3 * C_DIM);
  float* ckv_bias = alloc_f(2 * C_DIM);
  unsigned short* kbf_x = alloc_h((size_t)L_CTX * C_DIM);   // cross K bf16
  unsigned short* vtx   = alloc_h((size_t)C_DIM * L_CTX);   // cross V^T bf16

  // scratch aliases (lifetimes sequenced):
  //  self q/k bf16 live in x1b (x1b written only at self-O GEMM, after attn);
  //  self V^T lives in d_out (overwritten by cross-q bf16, then cross-O GEMM);
  //  FFN hidden (L_PAD x FFN_DIM bf16, 73.4MB) aliases qkv (74.3MB), whose
  //  contents (crossq/ckv) are dead before FFN1 runs.
  unsigned short* qbf_self = (unsigned short*)x1b;
  unsigned short* kbf_self = ((unsigned short*)x1b) + (size_t)L_SEQ * C_DIM;
  unsigned short* vt_self  = (unsigned short*)out;
  unsigned short* qbf_x    = (unsigned short*)out;
  float* crossq = qkv;                                   // cross Q f32 (packed 1536)
  float* ckv    = qkv + (size_t)L_SEQ * C_DIM;           // cross K/V f32 (512 x 3072)
  unsigned short* ffnh_bf = (unsigned short*)qkv;        // FFN hidden bf16

  const float qscale = 0.12751649737103347f;  // log2(e)/sqrt(128)

  dim3 gT(C_DIM / 32, C_DIM / 32);
  dim3 gQKV(3 * C_DIM / 128, L_PAD / 128);  // (36, 32)
  dim3 gGL64(C_DIM / 128, L_PAD / 64);      // (12, 64)  M64 variant
  dim3 gCKV64(2 * C_DIM / 128, L_CTX / 64); // (24, 8)   M64 variant
  dim3 gAtt(L_SEQ / 64, NHEAD);             // (63, 12)

  // weight transposes + converts
  transpose_bf16_kernel<<<gT, 256, 0, stream>>>(sa_wq, wtqkv, C_DIM, C_DIM);
  transpose_bf16_kernel<<<gT, 256, 0, stream>>>(sa_wk, wtqkv + (size_t)C_DIM * C_DIM, C_DIM, C_DIM);
  transpose_bf16_kernel<<<gT, 256, 0, stream>>>(sa_wv, wtqkv + (size_t)2 * C_DIM * C_DIM, C_DIM, C_DIM);
  transpose_bf16_kernel<<<gT, 256, 0, stream>>>(sa_wo, wto, C_DIM, C_DIM);
  transpose_bf16_kernel<<<gT, 256, 0, stream>>>(ca_wq, wtcq, C_DIM, C_DIM);
  transpose_bf16_kernel<<<gT, 256, 0, stream>>>(ca_wk, wtckv, C_DIM, C_DIM);
  transpose_bf16_kernel<<<gT, 256, 0, stream>>>(ca_wv, wtckv + (size_t)C_DIM * C_DIM, C_DIM, C_DIM);
  transpose_bf16_kernel<<<gT, 256, 0, stream>>>(ca_wo, wtco, C_DIM, C_DIM);
  transpose_bf16_kernel<<<dim3(FFN_DIM / 32, C_DIM / 32), 256, 0, stream>>>(ffn_w1, wt1, C_DIM, FFN_DIM);
  transpose_bf16_kernel<<<dim3(C_DIM / 32, FFN_DIM / 32), 256, 0, stream>>>(ffn_w2, wt2, FFN_DIM, C_DIM);
  f32_to_bf16_kernel<<<(L_CTX * C_DIM) / 1024, 256, 0, stream>>>(ctx_bf, ctx, L_CTX * C_DIM);
  concat3_kernel<<<6, 256, 0, stream>>>(qkv_bias, sa_bq, sa_bk, sa_bv);
  concat3_kernel<<<6, 256, 0, stream>>>(ckv_bias, ca_bk, ca_bv, nullptr);

  add_kernel<<<(6 * C_DIM + 255) / 256, 256, 0, stream>>>(em, e, mod, 6 * C_DIM);
  rope_tables_kernel<<<L_SEQ, 64, 0, stream>>>(cosb, sinb);

  // ---- self attention ----
  ln_affine_kernel<<<L_SEQ, 256, 0, stream>>>(act_bf, x, em + C_DIM, em, 1.f);
  mgemm_kernel<0><<<gQKV, 256, 0, stream>>>(act_bf, wtqkv, qkv_bias, qkv,
                                            nullptr, nullptr, 3 * C_DIM, C_DIM, L_SEQ);
  rms_post_kernel<1><<<L_SEQ, 256, 0, stream>>>(qbf_self, qkv, sa_nq, cosb, sinb,
                                                3 * C_DIM, qscale);
  rms_post_kernel<1><<<L_SEQ, 256, 0, stream>>>(kbf_self, qkv + C_DIM, sa_nk, cosb, sinb,
                                                3 * C_DIM, 1.f);
  transpose_v_kernel<<<dim3(L_SEQ / 32, C_DIM / 32), 256, 0, stream>>>(
      qkv + 2 * C_DIM, vt_self, 3 * C_DIM, L_SEQ);
  attn_mfma_kernel<<<gAtt, 256, 0, stream>>>(qbf_self, kbf_self, vt_self, act_bf, L_SEQ);
  mgemm64_kernel<2><<<gGL64, 256, 0, stream>>>(act_bf, wto, sa_bo, x1b,
                                               x, em + 2 * C_DIM, C_DIM, C_DIM, L_SEQ);

  // ---- cross attention ----
  ln_affine_kernel<<<L_SEQ, 256, 0, stream>>>(act_bf, x1b, n3_w, n3_b, 0.f);
  mgemm64_kernel<0><<<gGL64, 256, 0, stream>>>(act_bf, wtcq, ca_bq, crossq,
                                               nullptr, nullptr, C_DIM, C_DIM, L_SEQ);
  rms_post_kernel<0><<<L_SEQ, 256, 0, stream>>>(qbf_x, crossq, ca_nq, cosb, sinb,
                                                C_DIM, qscale);
  mgemm64_kernel<0><<<gCKV64, 256, 0, stream>>>(ctx_bf, wtckv, ckv_bias, ckv,
                                                nullptr, nullptr, 2 * C_DIM, C_DIM, L_CTX);
  rms_post_kernel<0><<<L_CTX, 256, 0, stream>>>(kbf_x, ckv, ca_nk, cosb, sinb,
                                                2 * C_DIM, 1.f);
  transpose_v_kernel<<<dim3(L_CTX / 32, C_DIM / 32), 256, 0, stream>>>(
      ckv + C_DIM, vtx, 2 * C_DIM, L_CTX);
  attn_mfma_kernel<<<gAtt, 256, 0, stream>>>(qbf_x, kbf_x, vtx, act_bf, L_CTX);
  mgemm64_kernel<2><<<gGL64, 256, 0, stream>>>(act_bf, wtco, ca_bo, out,
                                               x1b, nullptr, C_DIM, C_DIM, L_SEQ);

  // ---- FFN (un-chunked; hidden buffer aliases dead qkv) ----
  ln_affine_kernel<<<L_SEQ, 256, 0, stream>>>(act_bf, out, em + 4 * C_DIM, em + 3 * C_DIM, 1.f);
  dim3 g1(FFN_DIM / 128, L_PAD / 128);  // (70, 32)
  mgemm_kernel<1><<<g1, 256, 0, stream>>>(act_bf, wt1, ffn_b1, ffnh_bf,
                                          nullptr, nullptr, FFN_DIM, C_DIM, L_SEQ);
  dim3 g2(C_DIM / 128, L_PAD / 64);     // (12, 64)  M64 variant
  mgemm64_kernel<2><<<g2, 256, 0, stream>>>(ffnh_bf, wt2, ffn_b2, out,
                                            out, em + 5 * C_DIM, C_DIM, FFN_DIM, L_SEQ);
}

// Round 6
// 1529.789 us; speedup vs baseline: 1.0311x; 1.0311x over previous
//
#include <hip/hip_runtime.h>
#include <math.h>

// WanModel transformer block. Round 8:
//  - FFN2 (K=8960): BK=64 GEMM (128x128 tile, 2-buffer, stage-early/
//    wait-late) -> 32 MFMA/wave per barrier, 140 iters instead of 280.
//  - attn: 3-buffer depth-2 K/V staging with counted vmcnt(4) (mgemm-style),
//    52KB LDS -> 3 blocks/CU (matches grid 756 = 2.95/CU).
//  - rest unchanged from round 7.
// L=4032 (pad 4096), C=1536, NH=12, D=128, L2=512, FFN=8960.

#define L_SEQ 4032
#define L_PAD 4096
#define C_DIM 1536
#define L_CTX 512
#define FFN_DIM 8960
#define NHEAD 12
#define DHEAD 128

typedef __attribute__((ext_vector_type(8))) short short8;
typedef __attribute__((ext_vector_type(4))) float floatx4;

__device__ inline unsigned short f2bf(float x) {  // RNE f32 -> bf16
  unsigned int u = __float_as_uint(x);
  u += 0x7fffu + ((u >> 16) & 1u);
  return (unsigned short)(u >> 16);
}

// ---------------- block-wide reduction (256 threads = 4 waves) --------------
__device__ inline float2 block_sum2(float2 v) {
  __shared__ float2 red[4];
#pragma unroll
  for (int o = 32; o > 0; o >>= 1) {
    v.x += __shfl_xor(v.x, o, 64);
    v.y += __shfl_xor(v.y, o, 64);
  }
  int wave = threadIdx.x >> 6;
  if ((threadIdx.x & 63) == 0) red[wave] = v;
  __syncthreads();
  float2 t = make_float2(0.f, 0.f);
#pragma unroll
  for (int i = 0; i < 4; ++i) { t.x += red[i].x; t.y += red[i].y; }
  return t;
}

// ---------------- small elementwise kernels --------------------------------
__global__ void add_kernel(float* __restrict__ o, const float* __restrict__ a,
                           const float* __restrict__ b, int n) {
  int i = blockIdx.x * 256 + threadIdx.x;
  if (i < n) o[i] = a[i] + b[i];
}

__global__ void concat3_kernel(float* __restrict__ o, const float* __restrict__ a,
                               const float* __restrict__ b, const float* __restrict__ c) {
  int i = blockIdx.x * 256 + threadIdx.x;
  if (i < C_DIM) {
    o[i] = a[i];
    o[C_DIM + i] = b[i];
    if (c) o[2 * C_DIM + i] = c[i];
  }
}

__global__ void f32_to_bf16_kernel(unsigned short* __restrict__ o,
                                   const float* __restrict__ in, int n) {
  int i = (blockIdx.x * 256 + threadIdx.x) * 4;
  if (i < n) {
    float4 v = *(const float4*)&in[i];
    ushort4 o4 = {f2bf(v.x), f2bf(v.y), f2bf(v.z), f2bf(v.w)};
    *(ushort4*)&o[i] = o4;
  }
}

// W (K x N fp32, row-major) -> WT (N x K bf16, row-major)
__global__ __launch_bounds__(256) void transpose_bf16_kernel(
    const float* __restrict__ W, unsigned short* __restrict__ WT, int K, int N) {
  __shared__ float t[32][33];
  int n0 = blockIdx.x * 32, k0 = blockIdx.y * 32;
  int c = threadIdx.x & 31, r0 = threadIdx.x >> 5;
#pragma unroll
  for (int i = 0; i < 4; ++i) {
    int r = r0 + 8 * i;
    t[r][c] = W[(size_t)(k0 + r) * N + n0 + c];
  }
  __syncthreads();
#pragma unroll
  for (int i = 0; i < 4; ++i) {
    int r = r0 + 8 * i;
    WT[(size_t)(n0 + r) * K + k0 + c] = f2bf(t[c][r]);
  }
}

// V slice (Lk rows, stride floats) -> Vt (C x Lk bf16)
__global__ __launch_bounds__(256) void transpose_v_kernel(
    const float* __restrict__ V, unsigned short* __restrict__ Vt, int stride, int Lk) {
  __shared__ float t[32][33];
  int k0 = blockIdx.x * 32, c0 = blockIdx.y * 32;
  int c = threadIdx.x & 31, r0 = threadIdx.x >> 5;
#pragma unroll
  for (int i = 0; i < 4; ++i) {
    int r = r0 + 8 * i;
    t[r][c] = V[(size_t)(k0 + r) * stride + c0 + c];
  }
  __syncthreads();
#pragma unroll
  for (int i = 0; i < 4; ++i) {
    int r = r0 + 8 * i;
    Vt[(size_t)(c0 + r) * Lk + k0 + c] = f2bf(t[c][r]);
  }
}

// ---------------- LayerNorm with affine, bf16 output -----------------------
__global__ __launch_bounds__(256) void ln_affine_kernel(
    unsigned short* __restrict__ out, const float* __restrict__ in,
    const float* __restrict__ sc, const float* __restrict__ sh, float addOne) {
  int row = blockIdx.x;
  const float* xr = in + (size_t)row * C_DIM;
  float vals[C_DIM / 256];
  float2 p = make_float2(0.f, 0.f);
  int cnt = 0;
  for (int c = threadIdx.x; c < C_DIM; c += 256) {
    float v = xr[c];
    vals[cnt++] = v;
    p.x += v; p.y += v * v;
  }
  float2 t = block_sum2(p);
  float mean = t.x * (1.f / C_DIM);
  float var = t.y * (1.f / C_DIM) - mean * mean;
  float r = rsqrtf(var + 1e-6f);
  cnt = 0;
  for (int c = threadIdx.x; c < C_DIM; c += 256) {
    float xh = (vals[cnt++] - mean) * r;
    out[(size_t)row * C_DIM + c] = f2bf(xh * (addOne + sc[c]) + sh[c]);
  }
}

// ---------------- fused RMS norm (+RoPE) + bf16 cast -----------------------
template <int ROPE>
__global__ __launch_bounds__(256) void rms_post_kernel(
    unsigned short* __restrict__ obf, const float* __restrict__ in,
    const float* __restrict__ w, const float* __restrict__ cosb,
    const float* __restrict__ sinb, int stride, float ps) {
  int row = blockIdx.x;
  const float* xr = in + (size_t)row * stride;
  int c0 = threadIdx.x * 6;
  float v[6];
  *(float2*)&v[0] = *(const float2*)&xr[c0];
  *(float2*)&v[2] = *(const float2*)&xr[c0 + 2];
  *(float2*)&v[4] = *(const float2*)&xr[c0 + 4];
  float s2 = 0.f;
#pragma unroll
  for (int i = 0; i < 6; ++i) s2 += v[i] * v[i];
  float2 t = block_sum2(make_float2(s2, 0.f));
  float r = rsqrtf(t.x * (1.f / C_DIM) + 1e-6f) * ps;
#pragma unroll
  for (int i = 0; i < 6; ++i) v[i] *= r * w[c0 + i];
  if (ROPE) {
#pragma unroll
    for (int i = 0; i < 3; ++i) {
      int c = c0 + 2 * i;
      int j = (c & 127) >> 1;
      float co = cosb[row * 64 + j], si = sinb[row * 64 + j];
      float a = v[2 * i], b = v[2 * i + 1];
      v[2 * i] = a * co - b * si;
      v[2 * i + 1] = a * si + b * co;
    }
  }
  unsigned short* op = obf + (size_t)row * C_DIM + c0;
  ushort2 o01 = {f2bf(v[0]), f2bf(v[1])};
  ushort2 o23 = {f2bf(v[2]), f2bf(v[3])};
  ushort2 o45 = {f2bf(v[4]), f2bf(v[5])};
  *(ushort2*)&op[0] = o01;
  *(ushort2*)&op[2] = o23;
  *(ushort2*)&op[4] = o45;
}

// ---------------- RoPE tables ----------------------------------------------
__global__ void rope_tables_kernel(float* __restrict__ cosb, float* __restrict__ sinb) {
  int l = blockIdx.x, j = threadIdx.x;  // 64 threads
  int f = l / (16 * 28);
  int rem = l % (16 * 28);
  int hh = rem / 28, ww = rem % 28;
  double inv = pow(10000.0, -(double)(2 * j) / 128.0);
  double pos = (j < 22) ? (double)f : ((j < 43) ? (double)hh : (double)ww);
  double ang = pos * inv;
  cosb[l * 64 + j] = (float)cos(ang);
  sinb[l * 64 + j] = (float)sin(ang);
}

__device__ inline float gelu_tanh(float x) {
  float x3 = x * x * x;
  return 0.5f * x * (1.f + tanhf(0.79788456080286535588f * (x + 0.044715f * x3)));
}

// XCD-chunked bijective remap of the flat block index (T1 / m204)
__device__ inline int xcd_remap(int flat, int nwg) {
  int qq = nwg >> 3, rr = nwg & 7;
  int xcd = flat & 7, idx = flat >> 3;
  return (xcd < rr ? xcd * (qq + 1) : rr * (qq + 1) + (xcd - rr) * qq) + idx;
}

// ---------------- bf16 MFMA GEMM, tile 128x128, BK=32 (3-buffer) -----------
// C[m][n] = sum_k A[m][k]*BT[n][k] + bias[n].  Depth-2 prefetch, raw
// s_barrier + counted vmcnt(4).  EPI: 0 f32; 1 gelu+bf16; 2 resid+v*gate.
template <int EPI>
__global__ __launch_bounds__(256) void mgemm_kernel(
    const unsigned short* __restrict__ A, const unsigned short* __restrict__ BT,
    const float* __restrict__ bias, void* __restrict__ Cout,
    const float* __restrict__ resid, const float* __restrict__ gate,
    int N, int K, int Mlimit) {
  __shared__ short sA[3][4096];  // 128 x 32 bf16, fragment order
  __shared__ short sB[3][4096];
  const int tid = threadIdx.x;
  const int wv = tid >> 6, lane = tid & 63;
  const int lm = lane & 15, lq = lane >> 4;
  const int wr = wv >> 1, wc = wv & 1;

  const int gx = gridDim.x;
  int flat = xcd_remap(blockIdx.y * gx + blockIdx.x, gx * gridDim.y);
  const int row0 = (flat / gx) * 128, col0 = (flat % gx) * 128;

  floatx4 zero4 = {0.f, 0.f, 0.f, 0.f};
  floatx4 acc[4][4];
#pragma unroll
  for (int i = 0; i < 4; ++i)
#pragma unroll
    for (int j = 0; j < 4; ++j) acc[i][j] = zero4;

  const unsigned short* Abase = A + ((size_t)row0 + lm) * K + lq * 8;
  const unsigned short* Bbase = BT + ((size_t)col0 + lm) * K + lq * 8;

  auto stage = [&](int buf, int k0) {
#pragma unroll
    for (int t = 0; t < 2; ++t) {
      int g = wv * 2 + t;
      __builtin_amdgcn_global_load_lds(
          (const __attribute__((address_space(1))) void*)(Abase + (size_t)(g * 16) * K + k0),
          (__attribute__((address_space(3))) void*)(sA[buf] + g * 512), 16, 0, 0);
      __builtin_amdgcn_global_load_lds(
          (const __attribute__((address_space(1))) void*)(Bbase + (size_t)(g * 16) * K + k0),
          (__attribute__((address_space(3))) void*)(sB[buf] + g * 512), 16, 0, 0);
    }
  };

  stage(0, 0);
  stage(1, 32);
  asm volatile("s_waitcnt vmcnt(4)" ::: "memory");  // buf0 loads done
  __builtin_amdgcn_s_barrier();
  __builtin_amdgcn_sched_barrier(0);

  int cur = 0;
  const int nk = K >> 5;
  for (int t = 0; t < nk; ++t) {
    int b2 = cur + 2; if (b2 >= 3) b2 -= 3;
    const bool more = (t + 2 < nk);
    if (more) stage(b2, (t + 2) << 5);  // depth-2 prefetch
    const short* sAc = &sA[cur][0];
    const short* sBc = &sB[cur][0];
    short8 af[4], bfv[4];
#pragma unroll
    for (int mt = 0; mt < 4; ++mt)
      af[mt] = *(const short8*)(sAc + (wr * 4 + mt) * 512 + lane * 8);
#pragma unroll
    for (int nt = 0; nt < 4; ++nt)
      bfv[nt] = *(const short8*)(sBc + (wc * 4 + nt) * 512 + lane * 8);
#pragma unroll
    for (int mt = 0; mt < 4; ++mt)
#pragma unroll
      for (int nt = 0; nt < 4; ++nt)
        acc[mt][nt] = __builtin_amdgcn_mfma_f32_16x16x32_bf16(
            af[mt], bfv[nt], acc[mt][nt], 0, 0, 0);
    __builtin_amdgcn_sched_barrier(0);
    if (more) { asm volatile("s_waitcnt vmcnt(4)" ::: "memory"); }  // t+1 ready
    else      { asm volatile("s_waitcnt vmcnt(0)" ::: "memory"); }  // tail drain
    __builtin_amdgcn_s_barrier();
    __builtin_amdgcn_sched_barrier(0);
    cur = (cur + 1 == 3) ? 0 : cur + 1;
  }

#pragma unroll
  for (int nt = 0; nt < 4; ++nt) {
    int colg = col0 + wc * 64 + nt * 16 + lm;
    float bv = bias[colg];
    float gv = (EPI == 2 && gate) ? gate[colg] : 1.f;
#pragma unroll
    for (int mt = 0; mt < 4; ++mt) {
#pragma unroll
      for (int r = 0; r < 4; ++r) {
        int rowg = row0 + wr * 64 + mt * 16 + lq * 4 + r;
        if (rowg < Mlimit) {
          float v = acc[mt][nt][r] + bv;
          if (EPI == 1) {
            ((unsigned short*)Cout)[(size_t)rowg * N + colg] = f2bf(gelu_tanh(v));
          } else if (EPI == 2) {
            ((float*)Cout)[(size_t)rowg * N + colg] =
                resid[(size_t)rowg * N + colg] + v * gv;
          } else {
            ((float*)Cout)[(size_t)rowg * N + colg] = v;
          }
        }
      }
    }
  }
}

// ---------------- bf16 MFMA GEMM, tile 128x128, BK=64 (2-buffer) -----------
// For long-K GEMMs (FFN2, K=8960): 32 MFMA/wave per barrier, half the
// barrier count.  Stage issued BEFORE compute, drained after (stage-early/
// wait-late: prefetch latency hides under the 2x compute phase).  LDS 64KB
// -> 2 blocks/CU.  K%64==0.
template <int EPI>
__global__ __launch_bounds__(256) void mgemm_k64_kernel(
    const unsigned short* __restrict__ A, const unsigned short* __restrict__ BT,
    const float* __restrict__ bias, void* __restrict__ Cout,
    const float* __restrict__ resid, const float* __restrict__ gate,
    int N, int K, int Mlimit) {
  __shared__ short sA[2][8192];  // 128 x 64 bf16 = two 32-k subtiles
  __shared__ short sB[2][8192];
  const int tid = threadIdx.x;
  const int wv = tid >> 6, lane = tid & 63;
  const int lm = lane & 15, lq = lane >> 4;
  const int wr = wv >> 1, wc = wv & 1;

  const int gx = gridDim.x;
  int flat = xcd_remap(blockIdx.y * gx + blockIdx.x, gx * gridDim.y);
  const int row0 = (flat / gx) * 128, col0 = (flat % gx) * 128;

  floatx4 zero4 = {0.f, 0.f, 0.f, 0.f};
  floatx4 acc[4][4];
#pragma unroll
  for (int i = 0; i < 4; ++i)
#pragma unroll
    for (int j = 0; j < 4; ++j) acc[i][j] = zero4;

  const unsigned short* Abase = A + ((size_t)row0 + lm) * K + lq * 8;
  const unsigned short* Bbase = BT + ((size_t)col0 + lm) * K + lq * 8;

  auto stage = [&](int buf, int k0) {
#pragma unroll
    for (int kk = 0; kk < 2; ++kk) {
#pragma unroll
      for (int t = 0; t < 2; ++t) {
        int g = wv * 2 + t;
        __builtin_amdgcn_global_load_lds(
            (const __attribute__((address_space(1))) void*)(Abase + (size_t)(g * 16) * K + k0 + kk * 32),
            (__attribute__((address_space(3))) void*)(sA[buf] + kk * 4096 + g * 512), 16, 0, 0);
        __builtin_amdgcn_global_load_lds(
            (const __attribute__((address_space(1))) void*)(Bbase + (size_t)(g * 16) * K + k0 + kk * 32),
            (__attribute__((address_space(3))) void*)(sB[buf] + kk * 4096 + g * 512), 16, 0, 0);
      }
    }
  };

  stage(0, 0);
  asm volatile("s_waitcnt vmcnt(0)" ::: "memory");
  __builtin_amdgcn_s_barrier();
  __builtin_amdgcn_sched_barrier(0);

  int cur = 0;
  const int nk = K >> 6;
  for (int t = 0; t < nk; ++t) {
    if (t + 1 < nk) stage(cur ^ 1, (t + 1) << 6);  // issue early
#pragma unroll
    for (int kk = 0; kk < 2; ++kk) {
      const short* sAc = &sA[cur][kk * 4096];
      const short* sBc = &sB[cur][kk * 4096];
      short8 af[4], bfv[4];
#pragma unroll
      for (int mt = 0; mt < 4; ++mt)
        af[mt] = *(const short8*)(sAc + (wr * 4 + mt) * 512 + lane * 8);
#pragma unroll
      for (int nt = 0; nt < 4; ++nt)
        bfv[nt] = *(const short8*)(sBc + (wc * 4 + nt) * 512 + lane * 8);
#pragma unroll
      for (int mt = 0; mt < 4; ++mt)
#pragma unroll
        for (int nt = 0; nt < 4; ++nt)
          acc[mt][nt] = __builtin_amdgcn_mfma_f32_16x16x32_bf16(
              af[mt], bfv[nt], acc[mt][nt], 0, 0, 0);
    }
    __builtin_amdgcn_sched_barrier(0);
    asm volatile("s_waitcnt vmcnt(0)" ::: "memory");  // wait late
    __builtin_amdgcn_s_barrier();
    __builtin_amdgcn_sched_barrier(0);
    cur ^= 1;
  }

#pragma unroll
  for (int nt = 0; nt < 4; ++nt) {
    int colg = col0 + wc * 64 + nt * 16 + lm;
    float bv = bias[colg];
    float gv = (EPI == 2 && gate) ? gate[colg] : 1.f;
#pragma unroll
    for (int mt = 0; mt < 4; ++mt) {
#pragma unroll
      for (int r = 0; r < 4; ++r) {
        int rowg = row0 + wr * 64 + mt * 16 + lq * 4 + r;
        if (rowg < Mlimit) {
          float v = acc[mt][nt][r] + bv;
          if (EPI == 1) {
            ((unsigned short*)Cout)[(size_t)rowg * N + colg] = f2bf(gelu_tanh(v));
          } else if (EPI == 2) {
            ((float*)Cout)[(size_t)rowg * N + colg] =
                resid[(size_t)rowg * N + colg] + v * gv;
          } else {
            ((float*)Cout)[(size_t)rowg * N + colg] = v;
          }
        }
      }
    }
  }
}

// ---------------- bf16 MFMA GEMM, tile 64x128 (occupancy variant) ----------
template <int EPI>
__global__ __launch_bounds__(256) void mgemm64_kernel(
    const unsigned short* __restrict__ A, const unsigned short* __restrict__ BT,
    const float* __restrict__ bias, void* __restrict__ Cout,
    const float* __restrict__ resid, const float* __restrict__ gate,
    int N, int K, int Mlimit) {
  __shared__ short sA[3][2048];  // 64 x 32 bf16, fragment order (4 chunks)
  __shared__ short sB[3][4096];  // 128 x 32 bf16 (8 chunks)
  const int tid = threadIdx.x;
  const int wv = tid >> 6, lane = tid & 63;
  const int lm = lane & 15, lq = lane >> 4;
  const int wc = wv;  // 4 column groups of 32

  const int gx = gridDim.x;
  int flat = xcd_remap(blockIdx.y * gx + blockIdx.x, gx * gridDim.y);
  const int row0 = (flat / gx) * 64, col0 = (flat % gx) * 128;

  floatx4 zero4 = {0.f, 0.f, 0.f, 0.f};
  floatx4 acc[4][2];
#pragma unroll
  for (int i = 0; i < 4; ++i)
#pragma unroll
    for (int j = 0; j < 2; ++j) acc[i][j] = zero4;

  const unsigned short* Abase = A + ((size_t)row0 + lm) * K + lq * 8;
  const unsigned short* Bbase = BT + ((size_t)col0 + lm) * K + lq * 8;

  auto stage = [&](int buf, int k0) {
    __builtin_amdgcn_global_load_lds(
        (const __attribute__((address_space(1))) void*)(Abase + (size_t)(wv * 16) * K + k0),
        (__attribute__((address_space(3))) void*)(sA[buf] + wv * 512), 16, 0, 0);
#pragma unroll
    for (int t = 0; t < 2; ++t) {
      int g = wv * 2 + t;
      __builtin_amdgcn_global_load_lds(
          (const __attribute__((address_space(1))) void*)(Bbase + (size_t)(g * 16) * K + k0),
          (__attribute__((address_space(3))) void*)(sB[buf] + g * 512), 16, 0, 0);
    }
  };

  stage(0, 0);
  stage(1, 32);
  asm volatile("s_waitcnt vmcnt(3)" ::: "memory");  // buf0 loads done
  __builtin_amdgcn_s_barrier();
  __builtin_amdgcn_sched_barrier(0);

  int cur = 0;
  const int nk = K >> 5;
  for (int t = 0; t < nk; ++t) {
    int b2 = cur + 2; if (b2 >= 3) b2 -= 3;
    const bool more = (t + 2 < nk);
    if (more) stage(b2, (t + 2) << 5);  // depth-2 prefetch
    const short* sAc = &sA[cur][0];
    const short* sBc = &sB[cur][0];
    short8 af[4], bfv[2];
#pragma unroll
    for (int mt = 0; mt < 4; ++mt)
      af[mt] = *(const short8*)(sAc + mt * 512 + lane * 8);
#pragma unroll
    for (int nt = 0; nt < 2; ++nt)
      bfv[nt] = *(const short8*)(sBc + (wc * 2 + nt) * 512 + lane * 8);
#pragma unroll
    for (int mt = 0; mt < 4; ++mt)
#pragma unroll
      for (int nt = 0; nt < 2; ++nt)
        acc[mt][nt] = __builtin_amdgcn_mfma_f32_16x16x32_bf16(
            af[mt], bfv[nt], acc[mt][nt], 0, 0, 0);
    __builtin_amdgcn_sched_barrier(0);
    if (more) { asm volatile("s_waitcnt vmcnt(3)" ::: "memory"); }  // t+1 ready
    else      { asm volatile("s_waitcnt vmcnt(0)" ::: "memory"); }  // tail drain
    __builtin_amdgcn_s_barrier();
    __builtin_amdgcn_sched_barrier(0);
    cur = (cur + 1 == 3) ? 0 : cur + 1;
  }

#pragma unroll
  for (int nt = 0; nt < 2; ++nt) {
    int colg = col0 + wc * 32 + nt * 16 + lm;
    float bv = bias[colg];
    float gv = (EPI == 2 && gate) ? gate[colg] : 1.f;
#pragma unroll
    for (int mt = 0; mt < 4; ++mt) {
#pragma unroll
      for (int r = 0; r < 4; ++r) {
        int rowg = row0 + mt * 16 + lq * 4 + r;
        if (rowg < Mlimit) {
          float v = acc[mt][nt][r] + bv;
          if (EPI == 1) {
            ((unsigned short*)Cout)[(size_t)rowg * N + colg] = f2bf(gelu_tanh(v));
          } else if (EPI == 2) {
            ((float*)Cout)[(size_t)rowg * N + colg] =
                resid[(size_t)rowg * N + colg] + v * gv;
          } else {
            ((float*)Cout)[(size_t)rowg * N + colg] = v;
          }
        }
      }
    }
  }
}

// ---------------- bf16 MFMA flash attention (swapped QK^T, depth-2) --------
// Qb: bf16 (rows x C_DIM), PRE-SCALED by log2(e)/sqrt(d).  Kb: bf16.
// Vt: bf16 (C_DIM x Lk), Vt[h*128+d][k] = V[k][h*128+d].
// O: bf16 (rows x C_DIM).  Grid (L/64, NHEAD), block 256 = 4 waves.
// Per 32-key tile: S^T = mfma(K,Q) -> each lane holds 8 scores of ONE q-row
// (q=lane&15); softmax = reg ops + 2 shuffles.  3-buffer depth-2 K/V staging
// with counted vmcnt(4) (mgemm-style): the waited-on loads were issued a
// full tile earlier.  LDS 52KB -> 3 blocks/CU (grid 756 = 2.95/CU).
__global__ __launch_bounds__(256) void attn_mfma_kernel(
    const unsigned short* __restrict__ Qb, const unsigned short* __restrict__ Kb,
    const unsigned short* __restrict__ Vt, unsigned short* __restrict__ O,
    int Lk) {
  __shared__ short sK[3][4096];  // 8 groups (nt,dc): k-row k0+nt*16+lm, d=dc*32+lq*8
  __shared__ short sV[3][4096];  // 8 groups dg: d-row dg*16+lm, k=k0+lq*8
  __shared__ short sP[4][512];   // per-wave 16x32 P tile, A-frag order
  const int h = blockIdx.y;
  const int q0 = blockIdx.x * 64;
  const int tid = threadIdx.x;
  const int wv = tid >> 6, lane = tid & 63;
  const int lm = lane & 15, lq = lane >> 4;

  // Q fragments in registers: row = q0+wv*16+lm, d = dc*32 + lq*8
  short8 qf[4];
  {
    const unsigned short* qrow =
        Qb + (size_t)(q0 + wv * 16 + lm) * C_DIM + h * DHEAD + lq * 8;
#pragma unroll
    for (int dc = 0; dc < 4; ++dc) qf[dc] = *(const short8*)(qrow + dc * 32);
  }

  floatx4 zero4 = {0.f, 0.f, 0.f, 0.f};
  floatx4 acc[8];  // O accum: acc[dg][r] -> row lq*4+r, col dg*16+lm
#pragma unroll
  for (int g = 0; g < 8; ++g) acc[g] = zero4;
  float m = -1e30f, l = 0.f;  // per-thread, q = lm domain

  auto stageKV = [&](int buf, int k0) {
#pragma unroll
    for (int t = 0; t < 2; ++t) {
      int g = wv * 2 + t;
      int nt_ = g >> 2, dc = g & 3;
      const unsigned short* srck =
          Kb + (size_t)(k0 + nt_ * 16 + lm) * C_DIM + h * DHEAD + dc * 32 + lq * 8;
      __builtin_amdgcn_global_load_lds(
          (const __attribute__((address_space(1))) void*)srck,
          (__attribute__((address_space(3))) void*)(sK[buf] + g * 512), 16, 0, 0);
      const unsigned short* srcv =
          Vt + (size_t)(h * DHEAD + g * 16 + lm) * Lk + k0 + lq * 8;
      __builtin_amdgcn_global_load_lds(
          (const __attribute__((address_space(1))) void*)srcv,
          (__attribute__((address_space(3))) void*)(sV[buf] + g * 512), 16, 0, 0);
    }
  };

  stageKV(0, 0);
  stageKV(1, 32);
  asm volatile("s_waitcnt vmcnt(4)" ::: "memory");  // buf0's 4 loads done
  __builtin_amdgcn_s_barrier();
  __builtin_amdgcn_sched_barrier(0);

  int cur = 0;
  const int nsteps = Lk >> 5;
  for (int t = 0; t < nsteps; ++t) {
    int b2 = cur + 2; if (b2 >= 3) b2 -= 3;
    const bool more = (t + 2 < nsteps);
    if (more) stageKV(b2, (t + 2) << 5);  // depth-2 prefetch
    const short* sKc = &sK[cur][0];
    const short* sVc = &sV[cur][0];

    // S^T = K * Q^T: lane (lq,lm) gets S[k=nt*16+lq*4+r][q=lm]
    floatx4 s0 = zero4, s1 = zero4;
#pragma unroll
    for (int dc = 0; dc < 4; ++dc) {
      short8 kf0 = *(const short8*)(sKc + dc * 512 + lane * 8);
      short8 kf1 = *(const short8*)(sKc + (4 + dc) * 512 + lane * 8);
      s0 = __builtin_amdgcn_mfma_f32_16x16x32_bf16(kf0, qf[dc], s0, 0, 0, 0);
      s1 = __builtin_amdgcn_mfma_f32_16x16x32_bf16(kf1, qf[dc], s1, 0, 0, 0);
    }

    // row max: 7 reg fmax + 2 shuffles across the lq chain
    float mx = fmaxf(fmaxf(fmaxf(s0[0], s0[1]), fmaxf(s0[2], s0[3])),
                     fmaxf(fmaxf(s1[0], s1[1]), fmaxf(s1[2], s1[3])));
    mx = fmaxf(mx, __shfl_xor(mx, 16));
    mx = fmaxf(mx, __shfl_xor(mx, 32));
    bool need = mx > m + 11.5f;  // defer-max (log2 domain)
    if (__any((int)need)) {
      float mn = fmaxf(m, mx);
      float al = exp2f(m - mn);
      m = mn;
      l *= al;
      float ar[4];
#pragma unroll
      for (int r = 0; r < 4; ++r) ar[r] = __shfl(al, lq * 4 + r);  // q-domain xpose
#pragma unroll
      for (int g = 0; g < 8; ++g)
#pragma unroll
        for (int r = 0; r < 4; ++r) acc[g][r] *= ar[r];
    }
    // P = 2^(S - m); pack to bf16; row-sum
    float rs = 0.f;
    ushort4 pk0, pk1;
#pragma unroll
    for (int r = 0; r < 4; ++r) {
      float p = exp2f(s0[r] - m);
      rs += p;
      ((unsigned short*)&pk0)[r] = f2bf(p);
    }
#pragma unroll
    for (int r = 0; r < 4; ++r) {
      float p = exp2f(s1[r] - m);
      rs += p;
      ((unsigned short*)&pk1)[r] = f2bf(p);
    }
    rs += __shfl_xor(rs, 16);
    rs += __shfl_xor(rs, 32);
    l += rs;
    // write P to sP in A-frag chunk order (per-wave region, no barrier)
    {
      int baseq = (((lq >> 1) * 16 + lm) << 3) + ((lq & 1) << 2);
      *(ushort4*)&sP[wv][baseq] = pk0;
      *(ushort4*)&sP[wv][baseq + 256] = pk1;
    }
    asm volatile("" ::: "memory");  // keep DS write->read program order
    // PV: A = P[16q x 32k] frag, B = Vt d-rows (contraction over 32 keys)
    short8 pa = *(const short8*)(&sP[wv][lane * 8]);
#pragma unroll
    for (int g = 0; g < 8; ++g) {
      short8 vf = *(const short8*)(sVc + g * 512 + lane * 8);
      acc[g] = __builtin_amdgcn_mfma_f32_16x16x32_bf16(pa, vf, acc[g], 0, 0, 0);
    }
    __builtin_amdgcn_sched_barrier(0);
    if (more) { asm volatile("s_waitcnt vmcnt(4)" ::: "memory"); }  // t+1 ready
    else      { asm volatile("s_waitcnt vmcnt(0)" ::: "memory"); }  // tail drain
    __builtin_amdgcn_s_barrier();
    __builtin_amdgcn_sched_barrier(0);
    cur = (cur + 1 == 3) ? 0 : cur + 1;
  }

  float invl[4];
#pragma unroll
  for (int r = 0; r < 4; ++r) invl[r] = 1.f / __shfl(l, lq * 4 + r);
  unsigned short* orow =
      O + (size_t)(q0 + wv * 16 + lq * 4) * C_DIM + h * DHEAD + lm;
#pragma unroll
  for (int g = 0; g < 8; ++g) {
#pragma unroll
    for (int r = 0; r < 4; ++r) {
      orow[(size_t)r * C_DIM + g * 16] = f2bf(acc[g][r] * invl[r]);
    }
  }
}

// ---------------- orchestration --------------------------------------------
extern "C" void kernel_launch(void* const* d_in, const int* in_sizes, int n_in,
                              void* d_out, int out_size, void* d_ws, size_t ws_size,
                              hipStream_t stream) {
  const float* x     = (const float*)d_in[0];
  const float* e     = (const float*)d_in[1];
  const float* ctx   = (const float*)d_in[2];
  const float* mod   = (const float*)d_in[3];
  const float* sa_wq = (const float*)d_in[4];
  const float* sa_bq = (const float*)d_in[5];
  const float* sa_wk = (const float*)d_in[6];
  const float* sa_bk = (const float*)d_in[7];
  const float* sa_wv = (const float*)d_in[8];
  const float* sa_bv = (const float*)d_in[9];
  const float* sa_wo = (const float*)d_in[10];
  const float* sa_bo = (const float*)d_in[11];
  const float* sa_nq = (const float*)d_in[12];
  const float* sa_nk = (const float*)d_in[13];
  const float* n3_w  = (const float*)d_in[14];
  const float* n3_b  = (const float*)d_in[15];
  const float* ca_wq = (const float*)d_in[16];
  const float* ca_bq = (const float*)d_in[17];
  const float* ca_wk = (const float*)d_in[18];
  const float* ca_bk = (const float*)d_in[19];
  const float* ca_wv = (const float*)d_in[20];
  const float* ca_bv = (const float*)d_in[21];
  const float* ca_wo = (const float*)d_in[22];
  const float* ca_bo = (const float*)d_in[23];
  const float* ca_nq = (const float*)d_in[24];
  const float* ca_nk = (const float*)d_in[25];
  const float* ffn_w1 = (const float*)d_in[26];
  const float* ffn_b1 = (const float*)d_in[27];
  const float* ffn_w2 = (const float*)d_in[28];
  const float* ffn_b2 = (const float*)d_in[29];
  float* out = (float*)d_out;

  char* wsb = (char*)d_ws;
  auto alloc_f = [&](size_t n) { float* p = (float*)wsb; wsb += ((n * 4 + 255) / 256) * 256; return p; };
  auto alloc_h = [&](size_t n) { unsigned short* p = (unsigned short*)wsb; wsb += ((n * 2 + 255) / 256) * 256; return p; };

  float* em   = alloc_f(6 * C_DIM);
  float* cosb = alloc_f(L_SEQ * 64);
  float* sinb = alloc_f(L_SEQ * 64);
  float* qkv  = alloc_f((size_t)L_SEQ * 3 * C_DIM);  // fused QKV f32 out
  float* x1b  = alloc_f((size_t)L_SEQ * C_DIM);
  unsigned short* act_bf  = alloc_h((size_t)L_PAD * C_DIM);
  unsigned short* ctx_bf  = alloc_h((size_t)L_CTX * C_DIM);
  unsigned short* wtqkv = alloc_h((size_t)3 * C_DIM * C_DIM);
  unsigned short* wto   = alloc_h((size_t)C_DIM * C_DIM);
  unsigned short* wtcq  = alloc_h((size_t)C_DIM * C_DIM);
  unsigned short* wtckv = alloc_h((size_t)2 * C_DIM * C_DIM);
  unsigned short* wtco  = alloc_h((size_t)C_DIM * C_DIM);
  unsigned short* wt1   = alloc_h((size_t)FFN_DIM * C_DIM);  // (8960 x 1536)
  unsigned short* wt2   = alloc_h((size_t)C_DIM * FFN_DIM);  // (1536 x 8960)
  float* qkv_bias = alloc_f(3 * C_DIM);
  float* ckv_bias = alloc_f(2 * C_DIM);
  unsigned short* kbf_x = alloc_h((size_t)L_CTX * C_DIM);   // cross K bf16
  unsigned short* vtx   = alloc_h((size_t)C_DIM * L_CTX);   // cross V^T bf16

  // scratch aliases (lifetimes sequenced):
  //  self q/k bf16 live in x1b (x1b written only at self-O GEMM, after attn);
  //  self V^T lives in d_out (overwritten by cross-q bf16, then cross-O GEMM);
  //  FFN hidden (L_PAD x FFN_DIM bf16, 73.4MB) aliases qkv (74.3MB), whose
  //  contents (crossq/ckv) are dead before FFN1 runs.
  unsigned short* qbf_self = (unsigned short*)x1b;
  unsigned short* kbf_self = ((unsigned short*)x1b) + (size_t)L_SEQ * C_DIM;
  unsigned short* vt_self  = (unsigned short*)out;
  unsigned short* qbf_x    = (unsigned short*)out;
  float* crossq = qkv;                                   // cross Q f32 (packed 1536)
  float* ckv    = qkv + (size_t)L_SEQ * C_DIM;           // cross K/V f32 (512 x 3072)
  unsigned short* ffnh_bf = (unsigned short*)qkv;        // FFN hidden bf16

  const float qscale = 0.12751649737103347f;  // log2(e)/sqrt(128)

  dim3 gT(C_DIM / 32, C_DIM / 32);
  dim3 gQKV(3 * C_DIM / 128, L_PAD / 128);  // (36, 32)
  dim3 gGL64(C_DIM / 128, L_PAD / 64);      // (12, 64)  M64 variant
  dim3 gCKV64(2 * C_DIM / 128, L_CTX / 64); // (24, 8)   M64 variant
  dim3 gAtt(L_SEQ / 64, NHEAD);             // (63, 12)

  // weight transposes + converts
  transpose_bf16_kernel<<<gT, 256, 0, stream>>>(sa_wq, wtqkv, C_DIM, C_DIM);
  transpose_bf16_kernel<<<gT, 256, 0, stream>>>(sa_wk, wtqkv + (size_t)C_DIM * C_DIM, C_DIM, C_DIM);
  transpose_bf16_kernel<<<gT, 256, 0, stream>>>(sa_wv, wtqkv + (size_t)2 * C_DIM * C_DIM, C_DIM, C_DIM);
  transpose_bf16_kernel<<<gT, 256, 0, stream>>>(sa_wo, wto, C_DIM, C_DIM);
  transpose_bf16_kernel<<<gT, 256, 0, stream>>>(ca_wq, wtcq, C_DIM, C_DIM);
  transpose_bf16_kernel<<<gT, 256, 0, stream>>>(ca_wk, wtckv, C_DIM, C_DIM);
  transpose_bf16_kernel<<<gT, 256, 0, stream>>>(ca_wv, wtckv + (size_t)C_DIM * C_DIM, C_DIM, C_DIM);
  transpose_bf16_kernel<<<gT, 256, 0, stream>>>(ca_wo, wtco, C_DIM, C_DIM);
  transpose_bf16_kernel<<<dim3(FFN_DIM / 32, C_DIM / 32), 256, 0, stream>>>(ffn_w1, wt1, C_DIM, FFN_DIM);
  transpose_bf16_kernel<<<dim3(C_DIM / 32, FFN_DIM / 32), 256, 0, stream>>>(ffn_w2, wt2, FFN_DIM, C_DIM);
  f32_to_bf16_kernel<<<(L_CTX * C_DIM) / 1024, 256, 0, stream>>>(ctx_bf, ctx, L_CTX * C_DIM);
  concat3_kernel<<<6, 256, 0, stream>>>(qkv_bias, sa_bq, sa_bk, sa_bv);
  concat3_kernel<<<6, 256, 0, stream>>>(ckv_bias, ca_bk, ca_bv, nullptr);

  add_kernel<<<(6 * C_DIM + 255) / 256, 256, 0, stream>>>(em, e, mod, 6 * C_DIM);
  rope_tables_kernel<<<L_SEQ, 64, 0, stream>>>(cosb, sinb);

  // ---- self attention ----
  ln_affine_kernel<<<L_SEQ, 256, 0, stream>>>(act_bf, x, em + C_DIM, em, 1.f);
  mgemm_kernel<0><<<gQKV, 256, 0, stream>>>(act_bf, wtqkv, qkv_bias, qkv,
                                            nullptr, nullptr, 3 * C_DIM, C_DIM, L_SEQ);
  rms_post_kernel<1><<<L_SEQ, 256, 0, stream>>>(qbf_self, qkv, sa_nq, cosb, sinb,
                                                3 * C_DIM, qscale);
  rms_post_kernel<1><<<L_SEQ, 256, 0, stream>>>(kbf_self, qkv + C_DIM, sa_nk, cosb, sinb,
                                                3 * C_DIM, 1.f);
  transpose_v_kernel<<<dim3(L_SEQ / 32, C_DIM / 32), 256, 0, stream>>>(
      qkv + 2 * C_DIM, vt_self, 3 * C_DIM, L_SEQ);
  attn_mfma_kernel<<<gAtt, 256, 0, stream>>>(qbf_self, kbf_self, vt_self, act_bf, L_SEQ);
  mgemm64_kernel<2><<<gGL64, 256, 0, stream>>>(act_bf, wto, sa_bo, x1b,
                                               x, em + 2 * C_DIM, C_DIM, C_DIM, L_SEQ);

  // ---- cross attention ----
  ln_affine_kernel<<<L_SEQ, 256, 0, stream>>>(act_bf, x1b, n3_w, n3_b, 0.f);
  mgemm64_kernel<0><<<gGL64, 256, 0, stream>>>(act_bf, wtcq, ca_bq, crossq,
                                               nullptr, nullptr, C_DIM, C_DIM, L_SEQ);
  rms_post_kernel<0><<<L_SEQ, 256, 0, stream>>>(qbf_x, crossq, ca_nq, cosb, sinb,
                                                C_DIM, qscale);
  mgemm64_kernel<0><<<gCKV64, 256, 0, stream>>>(ctx_bf, wtckv, ckv_bias, ckv,
                                                nullptr, nullptr, 2 * C_DIM, C_DIM, L_CTX);
  rms_post_kernel<0><<<L_CTX, 256, 0, stream>>>(kbf_x, ckv, ca_nk, cosb, sinb,
                                                2 * C_DIM, 1.f);
  transpose_v_kernel<<<dim3(L_CTX / 32, C_DIM / 32), 256, 0, stream>>>(
      ckv + C_DIM, vtx, 2 * C_DIM, L_CTX);
  attn_mfma_kernel<<<gAtt, 256, 0, stream>>>(qbf_x, kbf_x, vtx, act_bf, L_CTX);
  mgemm64_kernel<2><<<gGL64, 256, 0, stream>>>(act_bf, wtco, ca_bo, out,
                                               x1b, nullptr, C_DIM, C_DIM, L_SEQ);

  // ---- FFN (un-chunked; hidden buffer aliases dead qkv) ----
  ln_affine_kernel<<<L_SEQ, 256, 0, stream>>>(act_bf, out, em + 4 * C_DIM, em + 3 * C_DIM, 1.f);
  dim3 g1(FFN_DIM / 128, L_PAD / 128);  // (70, 32)
  mgemm_kernel<1><<<g1, 256, 0, stream>>>(act_bf, wt1, ffn_b1, ffnh_bf,
                                          nullptr, nullptr, FFN_DIM, C_DIM, L_SEQ);
  dim3 g2(C_DIM / 128, L_PAD / 128);    // (12, 32)  BK=64 variant
  mgemm_k64_kernel<2><<<g2, 256, 0, stream>>>(ffnh_bf, wt2, ffn_b2, out,
                                              out, em + 5 * C_DIM, C_DIM, FFN_DIM, L_SEQ);
}